// Round 4
// baseline (12332.298 us; speedup 1.0000x reference)
//
#include <hip/hip_runtime.h>
#include <math.h>

// EntNet forward on MI355X.
// Sizes: VOC=32000, MEM=128, NSLOTS=20, NSENT=128, MAXLEN=32, QLEN=16, ANSLEN=8, B=64
//
//   prep_kernel : s gather + Ws = s@Ww.T + Vkey + q/a1/a2 means   (1108 blocks)
//   scan_kernel : 128 sequential steps, one workgroup per slot (20 blocks x 1024 thr)
//                 Per-thread weight slice = HALF a Uw row (64 VGPRs) so the total
//                 working set (~110 regs) fits under the 128-reg cap that a
//                 1024-thread block forces. Rounds 2-3 proved the allocator clamps
//                 to 128 regardless of __launch_bounds__ hints and spills anything
//                 bigger (11.6 ms, VALUBusy 0.8%). m-half partials combined via a
//                 padded LDS buffer; still exactly 2 barriers/step.
//   final_kernel: attention over slots + output softmax            (64 blocks)

// ---------------------------------------------------------------- prep
__global__ __launch_bounds__(128) void prep_kernel(
    const int* __restrict__ ids, const int* __restrict__ ques, const int* __restrict__ ans,
    const float* __restrict__ E, const float* __restrict__ Ww, const float* __restrict__ Wb,
    const float* __restrict__ Vw, const float* __restrict__ Vb, const float* __restrict__ skeys,
    float* __restrict__ sT, float* __restrict__ WsT, float* __restrict__ vkey,
    float* __restrict__ qv, float* __restrict__ a1v, float* __restrict__ a2v)
{
    const int bi  = blockIdx.x;
    const int tid = threadIdx.x;   // 128
    if (bi < 1024) {
        // block = (b, group of 8 t).  s row gather + Ws row matmul.
        const int b = bi >> 4;
        const int g = bi & 15;
        __shared__ float s_l[8][128];
        for (int tt = 0; tt < 8; ++tt) {
            const int t     = g * 8 + tt;
            const int token = ids[b * 4096 + t];      // flat (NSENT*MAXLEN)=4096, first 128
            const float v   = E[token * 128 + tid];   // E row 0 is zero in the input
            s_l[tt][tid] = v;
            sT[(t * 64 + b) * 128 + tid] = v;         // layout (t, b, m)
        }
        __syncthreads();
        float acc[8];
        const float wbn = Wb[tid];
        #pragma unroll
        for (int i = 0; i < 8; ++i) acc[i] = wbn;
        const float4* wrow = (const float4*)(Ww + tid * 128);   // thread = output n
        for (int m4 = 0; m4 < 32; ++m4) {
            const float4 w = wrow[m4];
            #pragma unroll
            for (int tt = 0; tt < 8; ++tt) {
                acc[tt] += s_l[tt][m4*4+0]*w.x + s_l[tt][m4*4+1]*w.y
                         + s_l[tt][m4*4+2]*w.z + s_l[tt][m4*4+3]*w.w;
            }
        }
        for (int tt = 0; tt < 8; ++tt)
            WsT[((g*8+tt) * 64 + b) * 128 + tid] = acc[tt];     // layout (t, b, n)
    } else if (bi < 1044) {
        // Vkey[j][n] = Vb[n] + sum_m skeys[j][m]*Vw[n][m]
        const int j = bi - 1024;
        __shared__ float k_l[128];
        k_l[tid] = skeys[j * 128 + tid];
        __syncthreads();
        float acc = Vb[tid];
        const float4* vrow = (const float4*)(Vw + tid * 128);
        for (int m4 = 0; m4 < 32; ++m4) {
            const float4 w = vrow[m4];
            acc += k_l[m4*4]*w.x + k_l[m4*4+1]*w.y + k_l[m4*4+2]*w.z + k_l[m4*4+3]*w.w;
        }
        vkey[j * 128 + tid] = acc;
    } else {
        // q / a1 / a2 means per batch row
        const int b = bi - 1044;
        float sq = 0.f, s1 = 0.f, s2 = 0.f;
        for (int i = 0; i < 16; ++i) sq += E[ques[b*16+i] * 128 + tid];
        for (int i = 0; i < 8;  ++i) s1 += E[ans[(b*8+i)*2+0] * 128 + tid];
        for (int i = 0; i < 8;  ++i) s2 += E[ans[(b*8+i)*2+1] * 128 + tid];
        qv [b*128+tid] = sq * (1.f/16.f);
        a1v[b*128+tid] = s1 * 0.125f;
        a2v[b*128+tid] = s2 * 0.125f;
    }
}

// ---------------------------------------------------------------- scan
// One block per slot j. 1024 threads = 16 waves (4 waves/SIMD, VGPR hard-cap 128).
//   thread = (n = tid&127, mh = (tid>>7)&1 m-half, bg = tid>>8 batch group of 16)
//   Weights: Uw[n][mh*64 .. mh*64+63] in 16 float4 regs (64 VGPRs) -> no spill.
//   Matmul U reads are wave-uniform broadcasts (mh/bg/bq/mc wave-uniform).
//   mh=1 stashes acc[16] partials in pc (stride 24 floats: 16B-aligned, 4-way
//   bank alias only) BEFORE B1; mh=0 combines after B1 and does the update.
//   U kept UNNORMALIZED in LDS (stride 129); scale inv_s in registers.
//   Exactly 2 __syncthreads per step.
__global__ __launch_bounds__(1024) void scan_kernel(
    const float* __restrict__ sT, const float* __restrict__ WsT,
    const float* __restrict__ vkey, const float* __restrict__ Uw,
    const float* __restrict__ Ub, const float* __restrict__ skeys,
    float* __restrict__ h_out)
{
    extern __shared__ float sm[];
    float* Um    = sm;                    // 64*129 = 8256
    float* pc    = Um + 64*129;           // 4*128*24 = 12288 (partials, mh=1 -> mh=0)
    float* ubvk  = pc + 4*128*24;         // 128
    float* key_l = ubvk + 128;            // 128
    float* g_l   = key_l + 128;           // 64
    float* wred  = g_l + 64;              // 16

    const int j   = blockIdx.x;
    const int tid = threadIdx.x;          // 1024
    const int n   = tid & 127;            // output column
    const int mh  = (tid >> 7) & 1;      // m-half (wave-uniform)
    const int bg  = tid >> 8;             // 0..3 batch group (wave-uniform)
    const int m0  = mh * 64;
    const int gb  = tid >> 4;             // gate: batch row 0..63
    const int gm  = (tid & 15) * 8;       // gate: m-slice

    // Half of Uw row n -> 16 float4 regs (one-time)
    float4 wreg[16];
    {
        const float4* wr = (const float4*)(Uw + n * 128 + m0);
        #pragma unroll
        for (int i = 0; i < 16; ++i) wreg[i] = wr[i];
    }
    for (int i = tid; i < 64 * 129; i += 1024) Um[i] = 0.f;
    if (tid < 128) {
        ubvk[tid]  = Ub[tid] + vkey[j * 128 + tid];
        key_l[tid] = skeys[j * 128 + tid];
    }
    __syncthreads();

    float inv_s = 1.f;                    // true mem = inv_s * U; U=0 initially
    float* prow = pc + (bg * 128 + n) * 24;

    for (int t = 0; t < 128; ++t) {
        // ---- gate: g[b] = sigmoid(inv*dot(s_t[b],U[b]) + dot(s_t[b],key)) ----
        {
            const float4* s4 = (const float4*)(sT + (t*64 + gb)*128 + gm);
            const float*  u  = Um + gb*129 + gm;
            const float*  k  = key_l + gm;
            float d1 = 0.f, d2 = 0.f;
            #pragma unroll
            for (int c = 0; c < 2; ++c) {
                const float4 sv = s4[c];
                d1 += sv.x*u[c*4+0] + sv.y*u[c*4+1] + sv.z*u[c*4+2] + sv.w*u[c*4+3];
                d2 += sv.x*k[c*4+0] + sv.y*k[c*4+1] + sv.z*k[c*4+2] + sv.w*k[c*4+3];
            }
            d1 += __shfl_xor(d1, 1, 64); d2 += __shfl_xor(d2, 1, 64);
            d1 += __shfl_xor(d1, 2, 64); d2 += __shfl_xor(d2, 2, 64);
            d1 += __shfl_xor(d1, 4, 64); d2 += __shfl_xor(d2, 4, 64);
            d1 += __shfl_xor(d1, 8, 64); d2 += __shfl_xor(d2, 8, 64);
            if ((tid & 15) == 0) g_l[gb] = 1.f / (1.f + expf(-(inv_s*d1 + d2)));
        }

        // ---- matmul partial over this thread's m-half ----
        float acc[16];
        #pragma unroll
        for (int bq = 0; bq < 4; ++bq) {
            const float* u0 = Um + (bg*16 + bq*4) * 129 + m0;
            float a0 = 0.f, a1 = 0.f, a2 = 0.f, a3 = 0.f;
            #pragma unroll
            for (int mc = 0; mc < 16; ++mc) {
                const float4 w   = wreg[mc];
                const float4 u_0 = *(const float4*)(u0 + 0*129 + mc*4);
                const float4 u_1 = *(const float4*)(u0 + 1*129 + mc*4);
                const float4 u_2 = *(const float4*)(u0 + 2*129 + mc*4);
                const float4 u_3 = *(const float4*)(u0 + 3*129 + mc*4);
                a0 += u_0.x*w.x + u_0.y*w.y + u_0.z*w.z + u_0.w*w.w;
                a1 += u_1.x*w.x + u_1.y*w.y + u_1.z*w.z + u_1.w*w.w;
                a2 += u_2.x*w.x + u_2.y*w.y + u_2.z*w.z + u_2.w*w.w;
                a3 += u_3.x*w.x + u_3.y*w.y + u_3.z*w.z + u_3.w*w.w;
            }
            acc[bq*4+0] = a0; acc[bq*4+1] = a1; acc[bq*4+2] = a2; acc[bq*4+3] = a3;
        }

        // mh=1: stash partials for the mh=0 partner (disjoint buffer; prev step's
        // pc reads finished before prev B2, so writing here pre-B1 is race-free)
        if (mh) {
            float4* p4 = (float4*)prow;
            p4[0] = make_float4(acc[0],  acc[1],  acc[2],  acc[3]);
            p4[1] = make_float4(acc[4],  acc[5],  acc[6],  acc[7]);
            p4[2] = make_float4(acc[8],  acc[9],  acc[10], acc[11]);
            p4[3] = make_float4(acc[12], acc[13], acc[14], acc[15]);
        }
        __syncthreads();   // B1: old-U reads complete, partials visible

        // ---- mh=0: combine halves + update own (b, n) entries ----
        float ssq = 0.f;
        if (!mh) {
            const float4* p4 = (const float4*)prow;
            const float4 p0 = p4[0], p1 = p4[1], p2 = p4[2], p3 = p4[3];
            const float pv[16] = {p0.x,p0.y,p0.z,p0.w, p1.x,p1.y,p1.z,p1.w,
                                  p2.x,p2.y,p2.z,p2.w, p3.x,p3.y,p3.z,p3.w};
            const float ub_n = ubvk[n];
            #pragma unroll
            for (int bb = 0; bb < 16; ++bb) {
                const int b = bg*16 + bb;
                const float full = acc[bb] + pv[bb];
                float hr = inv_s*full + ub_n + WsT[(t*64 + b)*128 + n];
                hr = fmaxf(hr, 0.f);                       // h_cand
                const float x = inv_s*Um[b*129 + n] + g_l[b]*hr;
                Um[b*129 + n] = x;
                ssq += x*x;
            }
        }
        #pragma unroll
        for (int m = 1; m < 64; m <<= 1) ssq += __shfl_xor(ssq, m, 64);
        if ((tid & 63) == 0) wred[tid >> 6] = ssq;
        __syncthreads();   // B2: U writes + wave partials visible
        float tot = 0.f;
        #pragma unroll
        for (int w = 0; w < 16; ++w) tot += wred[w];
        inv_s = 1.f / sqrtf(tot);
        // wred re-written only after next step's B1 -> safe
    }

    // h = inv * U  (normalized final memory), layout (b, j, m)
    if (!mh) {
        for (int bb = 0; bb < 16; ++bb) {
            const int b = bg*16 + bb;
            h_out[(b*20 + j)*128 + n] = inv_s * Um[b*129 + n];
        }
    }
}

// ---------------------------------------------------------------- final
__global__ __launch_bounds__(128) void final_kernel(
    const float* __restrict__ h, const float* __restrict__ qv,
    const float* __restrict__ a1v, const float* __restrict__ a2v,
    const float* __restrict__ Hw, const float* __restrict__ Hb,
    float* __restrict__ out)
{
    const int b   = blockIdx.x;
    const int tid = threadIdx.x;    // 128
    __shared__ float hb[20][128];
    __shared__ float ql[128];
    __shared__ float ul[128];
    __shared__ float pl[20];
    __shared__ float lgt[20];
    __shared__ float red1[2], red2[2];

    for (int jj = 0; jj < 20; ++jj) hb[jj][tid] = h[(b*20+jj)*128 + tid];
    ql[tid] = qv[b*128 + tid];
    __syncthreads();
    if (tid < 20) {
        float d = 0.f;
        for (int m = 0; m < 128; ++m) d += hb[tid][m] * ql[m];
        lgt[tid] = d;
    }
    __syncthreads();
    if (tid == 0) {
        float mx = lgt[0];
        for (int jj = 1; jj < 20; ++jj) mx = fmaxf(mx, lgt[jj]);
        float s = 0.f;
        for (int jj = 0; jj < 20; ++jj) { const float e = expf(lgt[jj]-mx); pl[jj] = e; s += e; }
        const float is = 1.f / s;
        for (int jj = 0; jj < 20; ++jj) pl[jj] *= is;
    }
    __syncthreads();
    float u = 0.f;
    for (int jj = 0; jj < 20; ++jj) u += pl[jj] * hb[jj][tid];
    ul[tid] = u;
    __syncthreads();
    float acc = ql[tid] + Hb[tid];
    const float4* hwr = (const float4*)(Hw + tid*128);
    for (int m4 = 0; m4 < 32; ++m4) {
        const float4 w = hwr[m4];
        acc += ul[m4*4]*w.x + ul[m4*4+1]*w.y + ul[m4*4+2]*w.z + ul[m4*4+3]*w.w;
    }
    const float r  = fmaxf(acc, 0.f);
    float y1 = r * a1v[b*128+tid];
    float y2 = r * a2v[b*128+tid];
    #pragma unroll
    for (int mask = 1; mask < 64; mask <<= 1) {
        y1 += __shfl_xor(y1, mask, 64);
        y2 += __shfl_xor(y2, mask, 64);
    }
    if ((tid & 63) == 0) { red1[tid>>6] = y1; red2[tid>>6] = y2; }
    __syncthreads();
    if (tid == 0) {
        const float z1 = red1[0] + red1[1];
        const float z2 = red2[0] + red2[1];
        const float mx = fmaxf(z1, z2);
        const float e1 = expf(z1-mx), e2 = expf(z2-mx);
        const float s  = e1 + e2;
        out[b*2+0] = e1 / s;
        out[b*2+1] = e2 / s;
    }
}

// ---------------------------------------------------------------- launch
extern "C" void kernel_launch(void* const* d_in, const int* in_sizes, int n_in,
                              void* d_out, int out_size, void* d_ws, size_t ws_size,
                              hipStream_t stream)
{
    const int*   ids  = (const int*)  d_in[0];
    const int*   ques = (const int*)  d_in[1];
    const int*   ans  = (const int*)  d_in[2];
    const float* E    = (const float*)d_in[3];
    const float* Uw   = (const float*)d_in[4];
    const float* Ubv  = (const float*)d_in[5];
    const float* Vw   = (const float*)d_in[6];
    const float* Vb   = (const float*)d_in[7];
    const float* Ww   = (const float*)d_in[8];
    const float* Wb   = (const float*)d_in[9];
    const float* sk   = (const float*)d_in[10];
    const float* Hw   = (const float*)d_in[11];
    const float* Hb   = (const float*)d_in[12];

    // workspace layout (floats): sT 1M | WsT 1M | vkey 2560 | qv/a1v/a2v 3*8192 | h 163840
    float* ws   = (float*)d_ws;
    float* sT   = ws;
    float* WsT  = sT  + 1048576;
    float* vkey = WsT + 1048576;
    float* qv   = vkey + 2560;
    float* a1v  = qv  + 8192;
    float* a2v  = a1v + 8192;
    float* h    = a2v + 8192;

    // dynamic LDS: Um 8256 + pc 12288 + ubvk 128 + key 128 + g 64 + wred 16 floats
    const int SCAN_LDS = (64*129 + 4*128*24 + 128 + 128 + 64 + 16) * (int)sizeof(float); // 83520
    hipFuncSetAttribute((const void*)scan_kernel,
                        hipFuncAttributeMaxDynamicSharedMemorySize, SCAN_LDS);

    prep_kernel<<<1108, 128, 0, stream>>>(ids, ques, ans, E, Ww, Wb, Vw, Vb, sk,
                                          sT, WsT, vkey, qv, a1v, a2v);
    scan_kernel<<<20, 1024, SCAN_LDS, stream>>>(sT, WsT, vkey, Uw, Ubv, sk, h);
    final_kernel<<<64, 128, 0, stream>>>(h, qv, a1v, a2v, Hw, Hb, (float*)d_out);
}

// Round 5
// 521.018 us; speedup vs baseline: 23.6696x; 23.6696x over previous
//
#include <hip/hip_runtime.h>
#include <math.h>

// EntNet forward on MI355X.
// Sizes: VOC=32000, MEM=128, NSLOTS=20, NSENT=128, MAXLEN=32, QLEN=16, ANSLEN=8, B=64
//
// R1-R4 lessons: (a) compiler defaults to 2 blocks/CU -> VGPR cap 128 (512thr) /
// 64 (1024thr); launch_bounds 2nd arg acts as min-BLOCKS (2 = no-op). Designs
// needing >cap regs spill to scratch catastrophically. (b) The fp32 designs are
// LDS *instruction-issue* bound (~4096 ds_read_b128/step/CU ~ 19.5K cyc/step).
// Fix: MFMA with hi/lo-split bf16 (3 products, ~2^-16 rel error) — fragments
// move 1KB/instr, cutting LDS issue ~4x and removing the 8.2K cyc VALU FMA floor.
// State U stays fp32 in LDS (ground truth); bf16 copies rebuilt each step.

typedef __attribute__((ext_vector_type(8))) short bf16x8;
typedef __attribute__((ext_vector_type(4))) float f32x4;

__device__ __forceinline__ unsigned short f2bh(float x) {   // f32 -> bf16 RNE
    unsigned int u = __float_as_uint(x);
    u += 0x7FFFu + ((u >> 16) & 1u);
    return (unsigned short)(u >> 16);
}
__device__ __forceinline__ float bh2f(unsigned short h) {
    return __uint_as_float(((unsigned int)h) << 16);
}

// ---------------------------------------------------------------- prep
__global__ __launch_bounds__(128) void prep_kernel(
    const int* __restrict__ ids, const int* __restrict__ ques, const int* __restrict__ ans,
    const float* __restrict__ E, const float* __restrict__ Ww, const float* __restrict__ Wb,
    const float* __restrict__ Vw, const float* __restrict__ Vb, const float* __restrict__ skeys,
    float* __restrict__ sT, float* __restrict__ WsT, float* __restrict__ vkey,
    float* __restrict__ qv, float* __restrict__ a1v, float* __restrict__ a2v)
{
    const int bi  = blockIdx.x;
    const int tid = threadIdx.x;   // 128
    if (bi < 1024) {
        const int b = bi >> 4;
        const int g = bi & 15;
        __shared__ float s_l[8][128];
        for (int tt = 0; tt < 8; ++tt) {
            const int t     = g * 8 + tt;
            const int token = ids[b * 4096 + t];
            const float v   = E[token * 128 + tid];
            s_l[tt][tid] = v;
            sT[(t * 64 + b) * 128 + tid] = v;         // layout (t, b, m)
        }
        __syncthreads();
        float acc[8];
        const float wbn = Wb[tid];
        #pragma unroll
        for (int i = 0; i < 8; ++i) acc[i] = wbn;
        const float4* wrow = (const float4*)(Ww + tid * 128);
        for (int m4 = 0; m4 < 32; ++m4) {
            const float4 w = wrow[m4];
            #pragma unroll
            for (int tt = 0; tt < 8; ++tt) {
                acc[tt] += s_l[tt][m4*4+0]*w.x + s_l[tt][m4*4+1]*w.y
                         + s_l[tt][m4*4+2]*w.z + s_l[tt][m4*4+3]*w.w;
            }
        }
        for (int tt = 0; tt < 8; ++tt)
            WsT[((g*8+tt) * 64 + b) * 128 + tid] = acc[tt];     // layout (t, b, n)
    } else if (bi < 1044) {
        const int j = bi - 1024;
        __shared__ float k_l[128];
        k_l[tid] = skeys[j * 128 + tid];
        __syncthreads();
        float acc = Vb[tid];
        const float4* vrow = (const float4*)(Vw + tid * 128);
        for (int m4 = 0; m4 < 32; ++m4) {
            const float4 w = vrow[m4];
            acc += k_l[m4*4]*w.x + k_l[m4*4+1]*w.y + k_l[m4*4+2]*w.z + k_l[m4*4+3]*w.w;
        }
        vkey[j * 128 + tid] = acc;
    } else {
        const int b = bi - 1044;
        float sq = 0.f, s1 = 0.f, s2 = 0.f;
        for (int i = 0; i < 16; ++i) sq += E[ques[b*16+i] * 128 + tid];
        for (int i = 0; i < 8;  ++i) s1 += E[ans[(b*8+i)*2+0] * 128 + tid];
        for (int i = 0; i < 8;  ++i) s2 += E[ans[(b*8+i)*2+1] * 128 + tid];
        qv [b*128+tid] = sq * (1.f/16.f);
        a1v[b*128+tid] = s1 * 0.125f;
        a2v[b*128+tid] = s2 * 0.125f;
    }
}

// ---------------------------------------------------------------- scan (MFMA)
// One block per slot j. 512 threads = 8 waves; wave = (bt = wave&3, nh = wave>>2).
// Per step: C[b][n] = sum_m U[b][m]*Uw[n][m] via mfma_f32_16x16x32_bf16 tiles
//   (4 bt x 8 nt x 4 kc); wave computes its bt x (nh*4..+3) tiles, 3 MFMAs per
//   (tile,kc) for the hi/lo split. A = U-frag [b=lane&15][k=quad*8+j] from Ah/Al;
//   B = W-frag [n=lane&15][k=quad*8+j] from Wh/Wl (static, built once).
// C/D: col(n) = lane&15, row(b-in-tile) = quad*4 + reg  [verified layout].
// Update happens in C layout: each lane owns 16 (b,n) entries, writes fp32 Um
// and the bf16 hi/lo copies for the next step. 2 barriers/step.
__global__ __launch_bounds__(512, 1) void scan_kernel(
    const float* __restrict__ sT, const float* __restrict__ WsT,
    const float* __restrict__ vkey, const float* __restrict__ Uw,
    const float* __restrict__ Ub, const float* __restrict__ skeys,
    float* __restrict__ h_out)
{
    extern __shared__ char smraw[];
    float*          Um   = (float*)smraw;                  // 64 x 132 fp32   (33792 B)
    unsigned short* Ah   = (unsigned short*)(smraw + 33792);   // 64 x 136 bf16 hi (17408 B)
    unsigned short* Al   = (unsigned short*)(smraw + 51200);   // 64 x 136 bf16 lo
    unsigned short* Wh   = (unsigned short*)(smraw + 68608);   // 128 x 136 bf16 hi (34816 B)
    unsigned short* Wl   = (unsigned short*)(smraw + 103424);  // 128 x 136 bf16 lo
    float*          key_l= (float*)(smraw + 138240);       // 128
    float*          g_l  = (float*)(smraw + 138752);       // 64
    float*          wred = (float*)(smraw + 139008);       // 8

    const int j    = blockIdx.x;
    const int tid  = threadIdx.x;        // 512
    const int wave = tid >> 6;           // 0..7
    const int lane = tid & 63;
    const int quad = lane >> 4;          // 0..3
    const int l16  = lane & 15;
    const int bt   = wave & 3;           // b-tile (rows of C)
    const int nh   = wave >> 2;          // n-half (4 n-tiles each)
    const int gb   = tid >> 3;           // gate: batch row 0..63
    const int gm   = (tid & 7) * 16;     // gate: m-slice (16 floats)

    // ---- one-time init ----
    // Wh/Wl: hi/lo bf16 split of Uw, row-major [n][m] stride 136
    {
        const int n  = tid >> 2;
        const int m0 = (tid & 3) * 32;
        const float* src = Uw + n * 128 + m0;
        unsigned int* dh = (unsigned int*)(Wh + n * 136 + m0);
        unsigned int* dl = (unsigned int*)(Wl + n * 136 + m0);
        #pragma unroll
        for (int c = 0; c < 16; ++c) {
            const float x0 = src[2*c], x1 = src[2*c+1];
            const unsigned short h0 = f2bh(x0), h1 = f2bh(x1);
            const unsigned short q0 = f2bh(x0 - bh2f(h0)), q1 = f2bh(x1 - bh2f(h1));
            dh[c] = (unsigned int)h0 | ((unsigned int)h1 << 16);
            dl[c] = (unsigned int)q0 | ((unsigned int)q1 << 16);
        }
    }
    for (int i = tid; i < 64*132; i += 512) Um[i] = 0.f;
    for (int i = tid; i < 4352;  i += 512) { ((unsigned int*)Ah)[i] = 0u; ((unsigned int*)Al)[i] = 0u; }
    if (tid < 128) key_l[tid] = skeys[j * 128 + tid];
    // per-lane static epilogue constants: ubv[nt] = Ub[n] + Vkey[j][n]
    float ubv[4];
    #pragma unroll
    for (int nt = 0; nt < 4; ++nt) {
        const int n = nh*64 + nt*16 + l16;
        ubv[nt] = Ub[n] + vkey[j*128 + n];
    }
    __syncthreads();

    float inv_s = 1.f;                   // true mem = inv_s * U; U = 0 initially

    for (int t = 0; t < 128; ++t) {
        // ---- prefetch WsT for this step's update (global, L2-resident) ----
        float wsv[4][4];
        #pragma unroll
        for (int nt = 0; nt < 4; ++nt) {
            const int n = nh*64 + nt*16 + l16;
            #pragma unroll
            for (int r = 0; r < 4; ++r) {
                const int b = bt*16 + quad*4 + r;
                wsv[nt][r] = WsT[(t*64 + b)*128 + n];
            }
        }

        // ---- gate: g[b] = sigmoid(inv*dot(s_t[b],U[b]) + dot(s_t[b],key)) ----
        {
            const float4* s4 = (const float4*)(sT + (t*64 + gb)*128 + gm);
            const float4* u4 = (const float4*)(Um + gb*132 + gm);
            const float4* k4 = (const float4*)(key_l + gm);
            float d1 = 0.f, d2 = 0.f;
            #pragma unroll
            for (int c = 0; c < 4; ++c) {
                const float4 sv = s4[c], uv = u4[c], kv = k4[c];
                d1 += sv.x*uv.x + sv.y*uv.y + sv.z*uv.z + sv.w*uv.w;
                d2 += sv.x*kv.x + sv.y*kv.y + sv.z*kv.z + sv.w*kv.w;
            }
            d1 += __shfl_xor(d1, 1, 64); d2 += __shfl_xor(d2, 1, 64);
            d1 += __shfl_xor(d1, 2, 64); d2 += __shfl_xor(d2, 2, 64);
            d1 += __shfl_xor(d1, 4, 64); d2 += __shfl_xor(d2, 4, 64);
            if ((tid & 7) == 0) g_l[gb] = 1.f / (1.f + expf(-(inv_s*d1 + d2)));
        }

        // ---- MFMA matmul: acc[nt] = C tile (bt, nh*4+nt) ----
        f32x4 acc[4] = {{0.f,0.f,0.f,0.f},{0.f,0.f,0.f,0.f},
                        {0.f,0.f,0.f,0.f},{0.f,0.f,0.f,0.f}};
        bf16x8 a_h[4], a_l[4];
        {
            const int arow = (bt*16 + l16) * 136 + quad*8;   // A row = b
            #pragma unroll
            for (int kc = 0; kc < 4; ++kc) {
                a_h[kc] = *(const bf16x8*)(Ah + arow + kc*32);
                a_l[kc] = *(const bf16x8*)(Al + arow + kc*32);
            }
        }
        #pragma unroll
        for (int nt = 0; nt < 4; ++nt) {
            const int brow = (nh*64 + nt*16 + l16) * 136 + quad*8;   // B row = n
            #pragma unroll
            for (int kc = 0; kc < 4; ++kc) {
                const bf16x8 b_h = *(const bf16x8*)(Wh + brow + kc*32);
                const bf16x8 b_l = *(const bf16x8*)(Wl + brow + kc*32);
                acc[nt] = __builtin_amdgcn_mfma_f32_16x16x32_bf16(a_h[kc], b_h, acc[nt], 0, 0, 0);
                acc[nt] = __builtin_amdgcn_mfma_f32_16x16x32_bf16(a_h[kc], b_l, acc[nt], 0, 0, 0);
                acc[nt] = __builtin_amdgcn_mfma_f32_16x16x32_bf16(a_l[kc], b_h, acc[nt], 0, 0, 0);
            }
        }
        __syncthreads();   // B1: all reads of old U/Ah/Al done; g_l visible

        // ---- update in C layout: lane owns (b = bt*16+quad*4+r, n = nh*64+nt*16+l16) ----
        const float4 gq = *(const float4*)(g_l + bt*16 + quad*4);   // g for the 4 rows
        const float gr[4] = {gq.x, gq.y, gq.z, gq.w};
        float ssq = 0.f;
        #pragma unroll
        for (int nt = 0; nt < 4; ++nt) {
            const int n = nh*64 + nt*16 + l16;
            #pragma unroll
            for (int r = 0; r < 4; ++r) {
                const int b = bt*16 + quad*4 + r;
                float hr = fmaf(inv_s, acc[nt][r], ubv[nt] + wsv[nt][r]);
                hr = fmaxf(hr, 0.f);                          // h_cand
                const float x = fmaf(inv_s, Um[b*132 + n], gr[r]*hr);
                Um[b*132 + n] = x;
                const unsigned short xh = f2bh(x);
                Ah[b*136 + n] = xh;
                Al[b*136 + n] = f2bh(x - bh2f(xh));
                ssq = fmaf(x, x, ssq);
            }
        }
        #pragma unroll
        for (int m = 1; m < 64; m <<= 1) ssq += __shfl_xor(ssq, m, 64);
        if (lane == 0) wred[wave] = ssq;
        __syncthreads();   // B2: U/Ah/Al writes + wave partials visible
        float tot = 0.f;
        #pragma unroll
        for (int w = 0; w < 8; ++w) tot += wred[w];
        inv_s = 1.f / sqrtf(tot);
        // wred re-written only after next step's B1 -> safe
    }

    // ---- h = inv * U, layout (b, j, m) ----
    #pragma unroll
    for (int nt = 0; nt < 4; ++nt) {
        const int n = nh*64 + nt*16 + l16;
        #pragma unroll
        for (int r = 0; r < 4; ++r) {
            const int b = bt*16 + quad*4 + r;
            h_out[(b*20 + j)*128 + n] = inv_s * Um[b*132 + n];
        }
    }
}

// ---------------------------------------------------------------- final
__global__ __launch_bounds__(128) void final_kernel(
    const float* __restrict__ h, const float* __restrict__ qv,
    const float* __restrict__ a1v, const float* __restrict__ a2v,
    const float* __restrict__ Hw, const float* __restrict__ Hb,
    float* __restrict__ out)
{
    const int b   = blockIdx.x;
    const int tid = threadIdx.x;    // 128
    __shared__ float hb[20][128];
    __shared__ float ql[128];
    __shared__ float ul[128];
    __shared__ float pl[20];
    __shared__ float lgt[20];
    __shared__ float red1[2], red2[2];

    for (int jj = 0; jj < 20; ++jj) hb[jj][tid] = h[(b*20+jj)*128 + tid];
    ql[tid] = qv[b*128 + tid];
    __syncthreads();
    if (tid < 20) {
        float d = 0.f;
        for (int m = 0; m < 128; ++m) d += hb[tid][m] * ql[m];
        lgt[tid] = d;
    }
    __syncthreads();
    if (tid == 0) {
        float mx = lgt[0];
        for (int jj = 1; jj < 20; ++jj) mx = fmaxf(mx, lgt[jj]);
        float s = 0.f;
        for (int jj = 0; jj < 20; ++jj) { const float e = expf(lgt[jj]-mx); pl[jj] = e; s += e; }
        const float is = 1.f / s;
        for (int jj = 0; jj < 20; ++jj) pl[jj] *= is;
    }
    __syncthreads();
    float u = 0.f;
    for (int jj = 0; jj < 20; ++jj) u += pl[jj] * hb[jj][tid];
    ul[tid] = u;
    __syncthreads();
    float acc = ql[tid] + Hb[tid];
    const float4* hwr = (const float4*)(Hw + tid*128);
    for (int m4 = 0; m4 < 32; ++m4) {
        const float4 w = hwr[m4];
        acc += ul[m4*4]*w.x + ul[m4*4+1]*w.y + ul[m4*4+2]*w.z + ul[m4*4+3]*w.w;
    }
    const float r  = fmaxf(acc, 0.f);
    float y1 = r * a1v[b*128+tid];
    float y2 = r * a2v[b*128+tid];
    #pragma unroll
    for (int mask = 1; mask < 64; mask <<= 1) {
        y1 += __shfl_xor(y1, mask, 64);
        y2 += __shfl_xor(y2, mask, 64);
    }
    if ((tid & 63) == 0) { red1[tid>>6] = y1; red2[tid>>6] = y2; }
    __syncthreads();
    if (tid == 0) {
        const float z1 = red1[0] + red1[1];
        const float z2 = red2[0] + red2[1];
        const float mx = fmaxf(z1, z2);
        const float e1 = expf(z1-mx), e2 = expf(z2-mx);
        const float s  = e1 + e2;
        out[b*2+0] = e1 / s;
        out[b*2+1] = e2 / s;
    }
}

// ---------------------------------------------------------------- launch
extern "C" void kernel_launch(void* const* d_in, const int* in_sizes, int n_in,
                              void* d_out, int out_size, void* d_ws, size_t ws_size,
                              hipStream_t stream)
{
    const int*   ids  = (const int*)  d_in[0];
    const int*   ques = (const int*)  d_in[1];
    const int*   ans  = (const int*)  d_in[2];
    const float* E    = (const float*)d_in[3];
    const float* Uw   = (const float*)d_in[4];
    const float* Ubv  = (const float*)d_in[5];
    const float* Vw   = (const float*)d_in[6];
    const float* Vb   = (const float*)d_in[7];
    const float* Ww   = (const float*)d_in[8];
    const float* Wb   = (const float*)d_in[9];
    const float* sk   = (const float*)d_in[10];
    const float* Hw   = (const float*)d_in[11];
    const float* Hb   = (const float*)d_in[12];

    // workspace layout (floats): sT 1M | WsT 1M | vkey 2560 | qv/a1v/a2v 3*8192 | h 163840
    float* ws   = (float*)d_ws;
    float* sT   = ws;
    float* WsT  = sT  + 1048576;
    float* vkey = WsT + 1048576;
    float* qv   = vkey + 2560;
    float* a1v  = qv  + 8192;
    float* a2v  = a1v + 8192;
    float* h    = a2v + 8192;

    // dynamic LDS: Um 33792 + Ah/Al 2*17408 + Wh/Wl 2*34816 + key 512 + g 256 + wred 32
    const int SCAN_LDS = 139040;
    hipFuncSetAttribute((const void*)scan_kernel,
                        hipFuncAttributeMaxDynamicSharedMemorySize, SCAN_LDS);

    prep_kernel<<<1108, 128, 0, stream>>>(ids, ques, ans, E, Ww, Wb, Vw, Vb, sk,
                                          sT, WsT, vkey, qv, a1v, a2v);
    scan_kernel<<<20, 512, SCAN_LDS, stream>>>(sT, WsT, vkey, Uw, Ubv, sk, h);
    final_kernel<<<64, 128, 0, stream>>>(h, qv, a1v, a2v, Hw, Hb, (float*)d_out);
}